// Round 4
// baseline (227.960 us; speedup 1.0000x reference)
//
#include <hip/hip_runtime.h>
#include <hip/hip_bf16.h>
#include <stdint.h>

// MultiHeadAttention: B=2, P=2048, D_MODEL=1024, H=16, D=64, causal.
//
// R15: gemm128_core restructured to the single-barrier prefetch pipeline
// (T3 minimum-2-phase) that attn_k already uses: double-buffered LDS,
// issue next K-step's global_load_lds DMAs into buf^1 BEFORE computing
// buf cur, ONE __syncthreads per step (vmcnt(0) drain lands after the
// MFMA cluster instead of before it). R14's core issued the DMAs between
// two barriers with zero overlap -> every K-step exposed full memory
// latency (qkv 77us, MfmaUtil 12%, everything idle). Swizzle kept
// (bank conflicts measured 0). attn_k unchanged from R14.

typedef __bf16 bf16x8 __attribute__((ext_vector_type(8)));
typedef float f32x4 __attribute__((ext_vector_type(4)));
typedef unsigned short u16;

__device__ __forceinline__ u16 f2bf(float f) {
  unsigned u = __float_as_uint(f);
  u += 0x7fffu + ((u >> 16) & 1u);
  return (u16)(u >> 16);
}

// ---- X f32 -> bf16 (coalesced, 8 elems/thread) ----
__global__ __launch_bounds__(256) void xcvt_k(const float* __restrict__ in,
                                              u16* __restrict__ out) {
  int i = (blockIdx.x * 256 + threadIdx.x) * 8;
  float4 f0 = *reinterpret_cast<const float4*>(in + i);
  float4 f1 = *reinterpret_cast<const float4*>(in + i + 4);
  u16 tmp[8] = {f2bf(f0.x), f2bf(f0.y), f2bf(f0.z), f2bf(f0.w),
                f2bf(f1.x), f2bf(f1.y), f2bf(f1.z), f2bf(f1.w)};
  *reinterpret_cast<uint4*>(out + i) = *reinterpret_cast<uint4*>(tmp);
}

// ---- generic weight transpose+convert: in f32 [B][R][C] -> out bf16 [B][C][R] ----
__global__ __launch_bounds__(256) void transpose_cvt_k(const float* __restrict__ in,
                                                       u16* __restrict__ out,
                                                       int R, int C) {
  __shared__ u16 tile[64][80];
  int b = blockIdx.z;
  int r0 = blockIdx.x * 64, c0 = blockIdx.y * 64;
  const float* ip = in + (size_t)b * R * C;
  u16* op = out + (size_t)b * R * C;
  int t = threadIdx.x;
  int r = t >> 2, cb = (t & 3) * 16;
  const float4* src = reinterpret_cast<const float4*>(ip + (size_t)(r0 + r) * C + c0 + cb);
  u16 tmp[16];
#pragma unroll
  for (int v = 0; v < 4; v++) {
    float4 f = src[v];
    tmp[v * 4 + 0] = f2bf(f.x);
    tmp[v * 4 + 1] = f2bf(f.y);
    tmp[v * 4 + 2] = f2bf(f.z);
    tmp[v * 4 + 3] = f2bf(f.w);
  }
  *reinterpret_cast<uint4*>(&tile[r][cb]) = *reinterpret_cast<uint4*>(&tmp[0]);
  *reinterpret_cast<uint4*>(&tile[r][cb + 8]) = *reinterpret_cast<uint4*>(&tmp[8]);
  __syncthreads();
  int c = t >> 2, rb = (t & 3) * 16;
  uint4 outv[2];
  u16* tp = reinterpret_cast<u16*>(outv);
#pragma unroll
  for (int j = 0; j < 16; j++) tp[j] = tile[rb + j][c];
  uint4* dst = reinterpret_cast<uint4*>(op + (size_t)(c0 + c) * R + r0 + rb);
  dst[0] = outv[0];
  dst[1] = outv[1];
}

// ---- fused q/k/v weight transpose: z = 0..47 -> (sel = z>>4, head = z&15) ----
__global__ __launch_bounds__(256) void transpose_qkv_k(const float* __restrict__ Wq,
                                                       const float* __restrict__ Wk,
                                                       const float* __restrict__ Wv,
                                                       u16* __restrict__ outBase) {
  __shared__ u16 tile[64][80];
  int z = blockIdx.z;
  int sel = z >> 4, head = z & 15;
  const float* W = (sel == 0) ? Wq : (sel == 1 ? Wk : Wv);
  const float* ip = W + (size_t)head * 65536;           // [1024][64]
  u16* op = outBase + (size_t)sel * 1048576 + (size_t)head * 65536;  // [64][1024]
  int r0 = blockIdx.x * 64;                              // row block in R=1024
  int t = threadIdx.x;
  int r = t >> 2, cb = (t & 3) * 16;
  const float4* src = reinterpret_cast<const float4*>(ip + (size_t)(r0 + r) * 64 + cb);
  u16 tmp[16];
#pragma unroll
  for (int v = 0; v < 4; v++) {
    float4 f = src[v];
    tmp[v * 4 + 0] = f2bf(f.x);
    tmp[v * 4 + 1] = f2bf(f.y);
    tmp[v * 4 + 2] = f2bf(f.z);
    tmp[v * 4 + 3] = f2bf(f.w);
  }
  *reinterpret_cast<uint4*>(&tile[r][cb]) = *reinterpret_cast<uint4*>(&tmp[0]);
  *reinterpret_cast<uint4*>(&tile[r][cb + 8]) = *reinterpret_cast<uint4*>(&tmp[8]);
  __syncthreads();
  int c = t >> 2, rb = (t & 3) * 16;
  uint4 outv[2];
  u16* tp = reinterpret_cast<u16*>(outv);
#pragma unroll
  for (int j = 0; j < 16; j++) tp[j] = tile[rb + j][c];
  uint4* dst = reinterpret_cast<uint4*>(op + (size_t)c * 1024 + r0 + rb);
  dst[0] = outv[0];
  dst[1] = outv[1];
}

// ---- direct global->LDS DMA, 16B per lane (dest = wave-uniform base + lane*16) ----
__device__ __forceinline__ void gload16(const u16* g, u16* l) {
  __builtin_amdgcn_global_load_lds(
      (__attribute__((address_space(1))) void*)(g),
      (__attribute__((address_space(3))) void*)(l), 16, 0, 0);
}

// ====== 128x128 GEMM core: double-buffered single-barrier DMA pipeline ======
// LDS rows are 128B (linear dest, as gload_lds needs). Swizzle (rule #21):
// 16B chunk p at row r holds global chunk p ^ (r&7); stage pre-swizzles the
// per-lane SOURCE col, reads XOR their chunk index -> reads <=2-way.
// Per K-step: issue 8 DMAs for step+1 into buf^1, compute buf cur, ONE
// barrier (compiler's vmcnt(0) drain lands AFTER the MFMA cluster).
__device__ __forceinline__ void gemm128_core(const u16* __restrict__ A,
                                             const u16* __restrict__ BT,
                                             int m0, int n0,
                                             f32x4 (&acc)[4][4]) {
  __shared__ __align__(16) u16 As[2][128][64];
  __shared__ __align__(16) u16 Bs[2][128][64];
  int t = threadIdx.x, l = t & 63;
  int w = t >> 6, wm = w & 1, wn = w >> 1;
  int l15 = l & 15, q4 = l >> 4;
  int r8 = l >> 3;                   // row within an 8-row gload group
  int cs = ((l & 7) ^ r8) * 8;       // pre-swizzled source chunk (u16 units)
  int swz = l15 & 7;                 // read-side row XOR key
  int srow = w * 32 + r8;
  const u16* ga = A + (size_t)(m0 + srow) * 1024 + cs;
  const u16* gb = BT + (size_t)(n0 + srow) * 1024 + cs;
  f32x4 z4 = {0.f, 0.f, 0.f, 0.f};
#pragma unroll
  for (int mi = 0; mi < 4; mi++)
#pragma unroll
    for (int nt = 0; nt < 4; nt++) acc[mi][nt] = z4;

  // prologue: stage k-step 0 into buffer 0
#pragma unroll
  for (int i = 0; i < 4; i++) {
    gload16(ga + (size_t)(i * 8) * 1024, &As[0][w * 32 + i * 8][0]);
    gload16(gb + (size_t)(i * 8) * 1024, &Bs[0][w * 32 + i * 8][0]);
  }
  __syncthreads();

  for (int step = 0; step < 16; step++) {
    int cur = step & 1;
    if (step < 15) {  // prefetch next K-step into buf^1; latency hides under MFMA
      int k0 = (step + 1) * 64;
#pragma unroll
      for (int i = 0; i < 4; i++) {
        gload16(ga + (size_t)(i * 8) * 1024 + k0, &As[cur ^ 1][w * 32 + i * 8][0]);
        gload16(gb + (size_t)(i * 8) * 1024 + k0, &Bs[cur ^ 1][w * 32 + i * 8][0]);
      }
    }
#pragma unroll
    for (int kk = 0; kk < 2; kk++) {
      bf16x8 af[4], bfr[4];
#pragma unroll
      for (int mi = 0; mi < 4; mi++)
        af[mi] = *reinterpret_cast<const bf16x8*>(
            &As[cur][wm * 64 + mi * 16 + l15][((kk * 4 + q4) ^ swz) * 8]);
#pragma unroll
      for (int nt = 0; nt < 4; nt++)
        bfr[nt] = *reinterpret_cast<const bf16x8*>(
            &Bs[cur][wn * 64 + nt * 16 + l15][((kk * 4 + q4) ^ swz) * 8]);
#pragma unroll
      for (int mi = 0; mi < 4; mi++)
#pragma unroll
        for (int nt = 0; nt < 4; nt++)
          acc[mi][nt] = __builtin_amdgcn_mfma_f32_16x16x32_bf16(af[mi], bfr[nt], acc[mi][nt], 0, 0, 0);
    }
    __syncthreads();  // single barrier: reads of cur done + prefetch DMA landed
  }
}

// QKV: A=Xb [4096][1024], BT=[WqT|WkT|WvT] [3072][1024]; grid (32, 24).
// V written tile-blocked: VT2[bh][ktile(32)][d(64)][pc(64)].
__global__ __launch_bounds__(256) void qkv_gemm128_k(const u16* __restrict__ A,
                                                     const u16* __restrict__ BT,
                                                     u16* __restrict__ Q,
                                                     u16* __restrict__ K,
                                                     u16* __restrict__ VT2) {
  const float QSCALE = 0.125f * 1.44269504088896340736f;  // (1/sqrt(64))*log2(e)
  int m0 = blockIdx.x * 128, n0 = blockIdx.y * 128;
  f32x4 acc[4][4];
  gemm128_core(A, BT, m0, n0, acc);
  int t = threadIdx.x, l = t & 63;
  int w = t >> 6, wm = w & 1, wn = w >> 1;
  int l15 = l & 15, q4 = l >> 4;
#pragma unroll
  for (int mi = 0; mi < 4; mi++) {
#pragma unroll
    for (int nt = 0; nt < 4; nt++) {
#pragma unroll
      for (int r = 0; r < 4; r++) {
        int m = m0 + wm * 64 + mi * 16 + q4 * 4 + r;
        int n = n0 + wn * 64 + nt * 16 + l15;
        int wsel = n >> 10, h = (n >> 6) & 15, d = n & 63;
        int b = m >> 11, p = m & 2047;
        size_t bh = (size_t)(b * 16 + h);
        float v = acc[mi][nt][r];
        if (wsel == 0)
          Q[(bh * 2048 + p) * 64 + d] = f2bf(v * QSCALE);
        else if (wsel == 1)
          K[(bh * 2048 + p) * 64 + d] = f2bf(v);
        else
          VT2[((bh * 32 + (p >> 6)) * 64 + d) * 64 + (p & 63)] = f2bf(v);
      }
    }
  }
}

// OUT: A=Ab [4096][1024], BT=WoT [1024][1024], O f32; grid (32, 8).
__global__ __launch_bounds__(256) void out_gemm128_k(const u16* __restrict__ A,
                                                     const u16* __restrict__ BT,
                                                     float* __restrict__ O) {
  int m0 = blockIdx.x * 128, n0 = blockIdx.y * 128;
  f32x4 acc[4][4];
  gemm128_core(A, BT, m0, n0, acc);
  int t = threadIdx.x, l = t & 63;
  int w = t >> 6, wm = w & 1, wn = w >> 1;
  int l15 = l & 15, q4 = l >> 4;
#pragma unroll
  for (int mi = 0; mi < 4; mi++) {
#pragma unroll
    for (int nt = 0; nt < 4; nt++) {
#pragma unroll
      for (int r = 0; r < 4; r++) {
        int m = m0 + wm * 64 + mi * 16 + q4 * 4 + r;
        int n = n0 + wn * 64 + nt * 16 + l15;
        O[(size_t)m * 1024 + n] = acc[mi][nt][r];
      }
    }
  }
}

// -------- flash attention: QBLK=128, 1 q-tile/block, gload_lds staging --------
// grid (16,16,2) = 512 blocks -> 2/CU. Blocks c and c+256 co-reside (round-robin
// heuristic): qt = b?15-pr:pr makes each CU's pair sum to 36 kt-iters.
// Per kt-iter: issue next tile's 4 gload_lds DMAs into buf^1 -> QK -> softmax
// -> PV -> one __syncthreads (vmcnt drain lands the prefetch).
__global__ __launch_bounds__(256) void attn_k(const u16* __restrict__ Q,
                                              const u16* __restrict__ K,
                                              const u16* __restrict__ VT2,
                                              u16* __restrict__ A) {
  __shared__ __align__(16) u16 Ks[2][64][64];
  __shared__ __align__(16) u16 Vs[2][64][64];
  __shared__ u16 P[4][32][72];   // wave-private; stride 72: 2-way writes, 16B-ish reads
  int pr = blockIdx.x, h = blockIdx.y, b = blockIdx.z;
  int qt = b ? (15 - pr) : pr;
  size_t bh = (size_t)(b * 16 + h);
  const u16* Qp = Q + bh * 2048 * 64;
  const u16* Kp = K + bh * 2048 * 64;
  const u16* Vt = VT2 + bh * 32 * 64 * 64;   // [kt][d][64]
  int t = threadIdx.x, l = t & 63, w = t >> 6;
  int l15 = l & 15, q4 = l >> 4;
  int r8 = l >> 3, cs = ((l & 7) ^ r8) * 8;  // staging source pre-swizzle
  int swz = l15 & 7;                          // fragment-read XOR key
  const float NEG = -1e30f;
  f32x4 z4 = {0.f, 0.f, 0.f, 0.f};
  int nkt = 2 * qt + 2;
  // wave w stages rows [w*16, w*16+16) of both tiles; 2 gloads each of K and V
  const u16* kbase = Kp + (size_t)(w * 16 + r8) * 64 + cs;
  const u16* vbase = Vt + (size_t)(w * 16 + r8) * 64 + cs;

  int qr0 = qt * 128 + w * 32;
  bf16x8 qf[2][2];
#pragma unroll
  for (int mi = 0; mi < 2; mi++) {
    const u16* qp = Qp + (size_t)(qr0 + mi * 16 + l15) * 64;
    qf[mi][0] = *reinterpret_cast<const bf16x8*>(qp + q4 * 8);
    qf[mi][1] = *reinterpret_cast<const bf16x8*>(qp + 32 + q4 * 8);
  }
  f32x4 accO[2][4];
  float rs[2][4];
#pragma unroll
  for (int mi = 0; mi < 2; mi++) {
#pragma unroll
    for (int nt = 0; nt < 4; nt++) accO[mi][nt] = z4;
#pragma unroll
    for (int r = 0; r < 4; r++) rs[mi][r] = 0.f;
  }

  // prologue: DMA tile kt=0 into buffer 0
#pragma unroll
  for (int j = 0; j < 2; j++) {
    gload16(kbase + (size_t)(j * 512), &Ks[0][w * 16 + j * 8][0]);
    gload16(vbase + (size_t)(j * 512), &Vs[0][w * 16 + j * 8][0]);
  }
  __syncthreads();

  for (int kt = 0; kt < nkt; kt++) {
    int cur = kt & 1;
    if (kt < nkt - 1) {  // prefetch next tile into buf^1; lands at the barrier
      size_t off = (size_t)(kt + 1) * 4096;
#pragma unroll
      for (int j = 0; j < 2; j++) {
        gload16(kbase + off + j * 512, &Ks[cur ^ 1][w * 16 + j * 8][0]);
        gload16(vbase + off + j * 512, &Vs[cur ^ 1][w * 16 + j * 8][0]);
      }
    }

    f32x4 s[2][4];
#pragma unroll
    for (int mi = 0; mi < 2; mi++)
#pragma unroll
      for (int nt = 0; nt < 4; nt++) s[mi][nt] = z4;
    __builtin_amdgcn_s_setprio(1);
#pragma unroll
    for (int kk = 0; kk < 2; kk++) {
      bf16x8 kf[4];
#pragma unroll
      for (int nt = 0; nt < 4; nt++)
        kf[nt] = *reinterpret_cast<const bf16x8*>(
            &Ks[cur][nt * 16 + l15][((kk * 4 + q4) ^ swz) * 8]);
#pragma unroll
      for (int mi = 0; mi < 2; mi++)
#pragma unroll
        for (int nt = 0; nt < 4; nt++)
          s[mi][nt] = __builtin_amdgcn_mfma_f32_16x16x32_bf16(qf[mi][kk], kf[nt], s[mi][nt], 0, 0, 0);
    }
    __builtin_amdgcn_s_setprio(0);
    if (kt >= 2 * qt) {  // causal masking (last two kv tiles of this q tile)
      int colbase = (kt - 2 * qt) * 64;
      int rowl = w * 32 + q4 * 4;
#pragma unroll
      for (int mi = 0; mi < 2; mi++)
#pragma unroll
        for (int nt = 0; nt < 4; nt++)
#pragma unroll
          for (int r = 0; r < 4; r++)
            if (colbase + nt * 16 + l15 > rowl + mi * 16 + r) s[mi][nt][r] = NEG;
    }
    // fixed-max softmax numerator: p = 2^s (s already log2-domain)
#pragma unroll
    for (int mi = 0; mi < 2; mi++)
#pragma unroll
      for (int nt = 0; nt < 4; nt++)
#pragma unroll
        for (int r = 0; r < 4; r++) {
          float p = exp2f(s[mi][nt][r]);
          rs[mi][r] += p;
          P[w][mi * 16 + q4 * 4 + r][nt * 16 + l15] = f2bf(p);
        }
    __builtin_amdgcn_s_setprio(1);
#pragma unroll
    for (int kk = 0; kk < 2; kk++) {
      bf16x8 pa[2];
#pragma unroll
      for (int mi = 0; mi < 2; mi++)
        pa[mi] = *reinterpret_cast<const bf16x8*>(&P[w][mi * 16 + l15][kk * 32 + q4 * 8]);
#pragma unroll
      for (int nt = 0; nt < 4; nt++) {
        bf16x8 vf = *reinterpret_cast<const bf16x8*>(
            &Vs[cur][nt * 16 + l15][((kk * 4 + q4) ^ swz) * 8]);
#pragma unroll
        for (int mi = 0; mi < 2; mi++)
          accO[mi][nt] = __builtin_amdgcn_mfma_f32_16x16x32_bf16(pa[mi], vf, accO[mi][nt], 0, 0, 0);
      }
    }
    __builtin_amdgcn_s_setprio(0);
    __syncthreads();  // single barrier: LDS reads done + prefetch DMA landed
  }

#pragma unroll
  for (int mi = 0; mi < 2; mi++)
#pragma unroll
    for (int r = 0; r < 4; r++) {
      float v = rs[mi][r];
#pragma unroll
      for (int sh = 1; sh < 16; sh <<= 1) v += __shfl_xor(v, sh, 64);
      float inv = 1.f / v;
      int prow = qt * 128 + w * 32 + mi * 16 + q4 * 4 + r;
      size_t base = ((size_t)(b * 2048 + prow)) * 1024 + h * 64;
#pragma unroll
      for (int nt = 0; nt < 4; nt++) A[base + nt * 16 + l15] = f2bf(accO[mi][nt][r] * inv);
    }
}

extern "C" void kernel_launch(void* const* d_in, const int* in_sizes, int n_in,
                              void* d_out, int out_size, void* d_ws, size_t ws_size,
                              hipStream_t stream) {
  const float* X  = (const float*)d_in[0];  // residual_stream [2][2048][1024]
  const float* Wq = (const float*)d_in[1];  // weight_query [16][1024][64]
  const float* Wk = (const float*)d_in[2];  // weight_key   [16][1024][64]
  const float* Wv = (const float*)d_in[3];  // weight_value [16][1024][64]
  const float* Wo = (const float*)d_in[4];  // weight_out   [1024][1024]
  float* out = (float*)d_out;               // [2][2048][1024] f32

  // WqT,WkT,WvT contiguous -> one BT stack [3072][1024] for the fused QKV GEMM.
  u16* ws = (u16*)d_ws;
  u16* WqT = ws;                    // [16][64][1024]
  u16* WoT = WqT + 3145728;         // [1024][1024]
  u16* Xb  = WoT + 1048576;         // [4096][1024] bf16 (dead after qkv)
  u16* Qb  = Xb + 4194304;          // [32][2048][64]
  u16* Kb  = Qb + 4194304;          // [32][2048][64]
  u16* VT2 = Kb + 4194304;          // [32][32][64][64] tile-blocked
  u16* Ab  = Xb;                    // aliases Xb; total 40 MB

  xcvt_k<<<dim3(2048), 256, 0, stream>>>(X, Xb);
  transpose_qkv_k<<<dim3(16, 1, 48), 256, 0, stream>>>(Wq, Wk, Wv, WqT);
  transpose_cvt_k<<<dim3(16, 16, 1), 256, 0, stream>>>(Wo, WoT, 1024, 1024);

  qkv_gemm128_k<<<dim3(32, 24), 256, 0, stream>>>(Xb, WqT, Qb, Kb, VT2);
  attn_k<<<dim3(16, 16, 2), 256, 0, stream>>>(Qb, Kb, VT2, Ab);
  out_gemm128_k<<<dim3(32, 8), 256, 0, stream>>>(Ab, WoT, out);
}

// Round 5
// 217.219 us; speedup vs baseline: 1.0494x; 1.0494x over previous
//
#include <hip/hip_runtime.h>
#include <hip/hip_bf16.h>
#include <stdint.h>

// MultiHeadAttention: B=2, P=2048, D_MODEL=1024, H=16, D=64, causal.
//
// R16: attn_k rewritten to 32x32x16 MFMA with swapped QK^T (T12, m214v22):
// S^T = mfma(K,Q) puts one q-row per lane (col=l&31) -> softmax is
// lane-local; P never touches LDS (cvt_pk_bf16 + permlane32_swap build the
// PV A-fragment in registers). R15 analysis: attn was LDS-pipe-saturated
// (425 cyc/wave/iter demand, x8 waves > iter window) with the P LDS
// round-trip on the serial chain; this cuts LDS to 192 cyc/wave/iter and
// removes the f2bf VALU (~128 instr/iter). GEMMs unchanged from R15.

typedef __bf16 bf16x8 __attribute__((ext_vector_type(8)));
typedef float f32x4 __attribute__((ext_vector_type(4)));
typedef float f32x16 __attribute__((ext_vector_type(16)));
typedef unsigned short u16;

__device__ __forceinline__ u16 f2bf(float f) {
  unsigned u = __float_as_uint(f);
  u += 0x7fffu + ((u >> 16) & 1u);
  return (u16)(u >> 16);
}

__device__ __forceinline__ uint32_t cvtpk(float lo, float hi) {
  uint32_t r;
  asm("v_cvt_pk_bf16_f32 %0, %1, %2" : "=v"(r) : "v"(lo), "v"(hi));
  return r;
}

// v_permlane32_swap_b32: a' = {a_low, b_low-to-high}, b' = {a_high-to-low, b_high}
__device__ __forceinline__ void pl32swap(uint32_t& a, uint32_t& b) {
  asm volatile("v_permlane32_swap_b32 %0, %1" : "+v"(a), "+v"(b));
}

// ---- X f32 -> bf16 (coalesced, 8 elems/thread) ----
__global__ __launch_bounds__(256) void xcvt_k(const float* __restrict__ in,
                                              u16* __restrict__ out) {
  int i = (blockIdx.x * 256 + threadIdx.x) * 8;
  float4 f0 = *reinterpret_cast<const float4*>(in + i);
  float4 f1 = *reinterpret_cast<const float4*>(in + i + 4);
  u16 tmp[8] = {f2bf(f0.x), f2bf(f0.y), f2bf(f0.z), f2bf(f0.w),
                f2bf(f1.x), f2bf(f1.y), f2bf(f1.z), f2bf(f1.w)};
  *reinterpret_cast<uint4*>(out + i) = *reinterpret_cast<uint4*>(tmp);
}

// ---- generic weight transpose+convert: in f32 [B][R][C] -> out bf16 [B][C][R] ----
__global__ __launch_bounds__(256) void transpose_cvt_k(const float* __restrict__ in,
                                                       u16* __restrict__ out,
                                                       int R, int C) {
  __shared__ u16 tile[64][80];
  int b = blockIdx.z;
  int r0 = blockIdx.x * 64, c0 = blockIdx.y * 64;
  const float* ip = in + (size_t)b * R * C;
  u16* op = out + (size_t)b * R * C;
  int t = threadIdx.x;
  int r = t >> 2, cb = (t & 3) * 16;
  const float4* src = reinterpret_cast<const float4*>(ip + (size_t)(r0 + r) * C + c0 + cb);
  u16 tmp[16];
#pragma unroll
  for (int v = 0; v < 4; v++) {
    float4 f = src[v];
    tmp[v * 4 + 0] = f2bf(f.x);
    tmp[v * 4 + 1] = f2bf(f.y);
    tmp[v * 4 + 2] = f2bf(f.z);
    tmp[v * 4 + 3] = f2bf(f.w);
  }
  *reinterpret_cast<uint4*>(&tile[r][cb]) = *reinterpret_cast<uint4*>(&tmp[0]);
  *reinterpret_cast<uint4*>(&tile[r][cb + 8]) = *reinterpret_cast<uint4*>(&tmp[8]);
  __syncthreads();
  int c = t >> 2, rb = (t & 3) * 16;
  uint4 outv[2];
  u16* tp = reinterpret_cast<u16*>(outv);
#pragma unroll
  for (int j = 0; j < 16; j++) tp[j] = tile[rb + j][c];
  uint4* dst = reinterpret_cast<uint4*>(op + (size_t)(c0 + c) * R + r0 + rb);
  dst[0] = outv[0];
  dst[1] = outv[1];
}

// ---- fused q/k/v weight transpose: z = 0..47 -> (sel = z>>4, head = z&15) ----
__global__ __launch_bounds__(256) void transpose_qkv_k(const float* __restrict__ Wq,
                                                       const float* __restrict__ Wk,
                                                       const float* __restrict__ Wv,
                                                       u16* __restrict__ outBase) {
  __shared__ u16 tile[64][80];
  int z = blockIdx.z;
  int sel = z >> 4, head = z & 15;
  const float* W = (sel == 0) ? Wq : (sel == 1 ? Wk : Wv);
  const float* ip = W + (size_t)head * 65536;           // [1024][64]
  u16* op = outBase + (size_t)sel * 1048576 + (size_t)head * 65536;  // [64][1024]
  int r0 = blockIdx.x * 64;                              // row block in R=1024
  int t = threadIdx.x;
  int r = t >> 2, cb = (t & 3) * 16;
  const float4* src = reinterpret_cast<const float4*>(ip + (size_t)(r0 + r) * 64 + cb);
  u16 tmp[16];
#pragma unroll
  for (int v = 0; v < 4; v++) {
    float4 f = src[v];
    tmp[v * 4 + 0] = f2bf(f.x);
    tmp[v * 4 + 1] = f2bf(f.y);
    tmp[v * 4 + 2] = f2bf(f.z);
    tmp[v * 4 + 3] = f2bf(f.w);
  }
  *reinterpret_cast<uint4*>(&tile[r][cb]) = *reinterpret_cast<uint4*>(&tmp[0]);
  *reinterpret_cast<uint4*>(&tile[r][cb + 8]) = *reinterpret_cast<uint4*>(&tmp[8]);
  __syncthreads();
  int c = t >> 2, rb = (t & 3) * 16;
  uint4 outv[2];
  u16* tp = reinterpret_cast<u16*>(outv);
#pragma unroll
  for (int j = 0; j < 16; j++) tp[j] = tile[rb + j][c];
  uint4* dst = reinterpret_cast<uint4*>(op + (size_t)c * 1024 + r0 + rb);
  dst[0] = outv[0];
  dst[1] = outv[1];
}

// ---- direct global->LDS DMA, 16B per lane (dest = wave-uniform base + lane*16) ----
__device__ __forceinline__ void gload16(const u16* g, u16* l) {
  __builtin_amdgcn_global_load_lds(
      (__attribute__((address_space(1))) void*)(g),
      (__attribute__((address_space(3))) void*)(l), 16, 0, 0);
}

// ====== 128x128 GEMM core: double-buffered single-barrier DMA pipeline ======
__device__ __forceinline__ void gemm128_core(const u16* __restrict__ A,
                                             const u16* __restrict__ BT,
                                             int m0, int n0,
                                             f32x4 (&acc)[4][4]) {
  __shared__ __align__(16) u16 As[2][128][64];
  __shared__ __align__(16) u16 Bs[2][128][64];
  int t = threadIdx.x, l = t & 63;
  int w = t >> 6, wm = w & 1, wn = w >> 1;
  int l15 = l & 15, q4 = l >> 4;
  int r8 = l >> 3;                   // row within an 8-row gload group
  int cs = ((l & 7) ^ r8) * 8;       // pre-swizzled source chunk (u16 units)
  int swz = l15 & 7;                 // read-side row XOR key
  int srow = w * 32 + r8;
  const u16* ga = A + (size_t)(m0 + srow) * 1024 + cs;
  const u16* gb = BT + (size_t)(n0 + srow) * 1024 + cs;
  f32x4 z4 = {0.f, 0.f, 0.f, 0.f};
#pragma unroll
  for (int mi = 0; mi < 4; mi++)
#pragma unroll
    for (int nt = 0; nt < 4; nt++) acc[mi][nt] = z4;

  // prologue: stage k-step 0 into buffer 0
#pragma unroll
  for (int i = 0; i < 4; i++) {
    gload16(ga + (size_t)(i * 8) * 1024, &As[0][w * 32 + i * 8][0]);
    gload16(gb + (size_t)(i * 8) * 1024, &Bs[0][w * 32 + i * 8][0]);
  }
  __syncthreads();

  for (int step = 0; step < 16; step++) {
    int cur = step & 1;
    if (step < 15) {  // prefetch next K-step into buf^1; latency hides under MFMA
      int k0 = (step + 1) * 64;
#pragma unroll
      for (int i = 0; i < 4; i++) {
        gload16(ga + (size_t)(i * 8) * 1024 + k0, &As[cur ^ 1][w * 32 + i * 8][0]);
        gload16(gb + (size_t)(i * 8) * 1024 + k0, &Bs[cur ^ 1][w * 32 + i * 8][0]);
      }
    }
#pragma unroll
    for (int kk = 0; kk < 2; kk++) {
      bf16x8 af[4], bfr[4];
#pragma unroll
      for (int mi = 0; mi < 4; mi++)
        af[mi] = *reinterpret_cast<const bf16x8*>(
            &As[cur][wm * 64 + mi * 16 + l15][((kk * 4 + q4) ^ swz) * 8]);
#pragma unroll
      for (int nt = 0; nt < 4; nt++)
        bfr[nt] = *reinterpret_cast<const bf16x8*>(
            &Bs[cur][wn * 64 + nt * 16 + l15][((kk * 4 + q4) ^ swz) * 8]);
#pragma unroll
      for (int mi = 0; mi < 4; mi++)
#pragma unroll
        for (int nt = 0; nt < 4; nt++)
          acc[mi][nt] = __builtin_amdgcn_mfma_f32_16x16x32_bf16(af[mi], bfr[nt], acc[mi][nt], 0, 0, 0);
    }
    __syncthreads();  // single barrier: reads of cur done + prefetch DMA landed
  }
}

// QKV: A=Xb [4096][1024], BT=[WqT|WkT|WvT] [3072][1024]; grid (32, 24).
// V written tile-blocked: VT2[bh][ktile(32)][d(64)][pc(64)].
__global__ __launch_bounds__(256) void qkv_gemm128_k(const u16* __restrict__ A,
                                                     const u16* __restrict__ BT,
                                                     u16* __restrict__ Q,
                                                     u16* __restrict__ K,
                                                     u16* __restrict__ VT2) {
  const float QSCALE = 0.125f * 1.44269504088896340736f;  // (1/sqrt(64))*log2(e)
  int m0 = blockIdx.x * 128, n0 = blockIdx.y * 128;
  f32x4 acc[4][4];
  gemm128_core(A, BT, m0, n0, acc);
  int t = threadIdx.x, l = t & 63;
  int w = t >> 6, wm = w & 1, wn = w >> 1;
  int l15 = l & 15, q4 = l >> 4;
#pragma unroll
  for (int mi = 0; mi < 4; mi++) {
#pragma unroll
    for (int nt = 0; nt < 4; nt++) {
#pragma unroll
      for (int r = 0; r < 4; r++) {
        int m = m0 + wm * 64 + mi * 16 + q4 * 4 + r;
        int n = n0 + wn * 64 + nt * 16 + l15;
        int wsel = n >> 10, h = (n >> 6) & 15, d = n & 63;
        int b = m >> 11, p = m & 2047;
        size_t bh = (size_t)(b * 16 + h);
        float v = acc[mi][nt][r];
        if (wsel == 0)
          Q[(bh * 2048 + p) * 64 + d] = f2bf(v * QSCALE);
        else if (wsel == 1)
          K[(bh * 2048 + p) * 64 + d] = f2bf(v);
        else
          VT2[((bh * 32 + (p >> 6)) * 64 + d) * 64 + (p & 63)] = f2bf(v);
      }
    }
  }
}

// OUT: A=Ab [4096][1024], BT=WoT [1024][1024], O f32; grid (32, 8).
__global__ __launch_bounds__(256) void out_gemm128_k(const u16* __restrict__ A,
                                                     const u16* __restrict__ BT,
                                                     float* __restrict__ O) {
  int m0 = blockIdx.x * 128, n0 = blockIdx.y * 128;
  f32x4 acc[4][4];
  gemm128_core(A, BT, m0, n0, acc);
  int t = threadIdx.x, l = t & 63;
  int w = t >> 6, wm = w & 1, wn = w >> 1;
  int l15 = l & 15, q4 = l >> 4;
#pragma unroll
  for (int mi = 0; mi < 4; mi++) {
#pragma unroll
    for (int nt = 0; nt < 4; nt++) {
#pragma unroll
      for (int r = 0; r < 4; r++) {
        int m = m0 + wm * 64 + mi * 16 + q4 * 4 + r;
        int n = n0 + wn * 64 + nt * 16 + l15;
        O[(size_t)m * 1024 + n] = acc[mi][nt][r];
      }
    }
  }
}

// ---- flash attention: 32x32 swapped-QK^T, in-register softmax (T12) ----
// grid (16,16,2) = 512 blocks -> 2/CU; qt = b?15-pr:pr balances CU pairs.
// Wave w owns 32 q-rows (col=l&31 of the S^T tile). Per kt-iter:
// prefetch next K/V tile (gload_lds, XOR-swizzled source) -> S^T = mfma(K,Q)
// -> mask/exp2 in-register -> cvt_pk+permlane32_swap builds PV A-frags
// -> accO += mfma(pa, V) -> one barrier. P never touches LDS.
__global__ __launch_bounds__(256) void attn_k(const u16* __restrict__ Q,
                                              const u16* __restrict__ K,
                                              const u16* __restrict__ VT2,
                                              u16* __restrict__ A) {
  __shared__ __align__(16) u16 Ks[2][64][64];
  __shared__ __align__(16) u16 Vs[2][64][64];
  __shared__ float rsbuf[4][32];
  int pr = blockIdx.x, h = blockIdx.y, b = blockIdx.z;
  int qt = b ? (15 - pr) : pr;
  size_t bh = (size_t)(b * 16 + h);
  const u16* Qp = Q + bh * 2048 * 64;
  const u16* Kp = K + bh * 2048 * 64;
  const u16* Vt = VT2 + bh * 32 * 64 * 64;   // [kt][d(64)][pc(64)]
  int t = threadIdx.x, l = t & 63, w = t >> 6;
  int l31 = l & 31, hi = l >> 5;
  int r8 = l >> 3, cs = ((l & 7) ^ r8) * 8;  // staging source pre-swizzle
  int swz = l31 & 7;                          // fragment-read XOR key (row&7)
  const float NEG = -1e30f;
  int nkt = 2 * qt + 2;
  // wave w stages rows [w*16, w*16+16) of both tiles; 2 gloads each of K and V
  const u16* kbase = Kp + (size_t)(w * 16 + r8) * 64 + cs;
  const u16* vbase = Vt + (size_t)(w * 16 + r8) * 64 + cs;
  int qrow = qt * 128 + w * 32 + l31;        // this lane's q-row (S^T col)

  // Q as B-operand: qb[kc][j] = Q[qrow][d = 16*kc + 8*hi + j]
  bf16x8 qb[4];
#pragma unroll
  for (int kc = 0; kc < 4; kc++)
    qb[kc] = *reinterpret_cast<const bf16x8*>(Qp + (size_t)qrow * 64 + kc * 16 + hi * 8);

  f32x16 accO[2];
#pragma unroll
  for (int dh = 0; dh < 2; dh++)
#pragma unroll
    for (int r = 0; r < 16; r++) accO[dh][r] = 0.f;
  float rs = 0.f;

  // prologue: DMA tile kt=0 into buffer 0
#pragma unroll
  for (int j = 0; j < 2; j++) {
    gload16(kbase + (size_t)(j * 512), &Ks[0][w * 16 + j * 8][0]);
    gload16(vbase + (size_t)(j * 512), &Vs[0][w * 16 + j * 8][0]);
  }
  __syncthreads();

  for (int kt = 0; kt < nkt; kt++) {
    int cur = kt & 1;
    if (kt < nkt - 1) {  // prefetch next tile into buf^1; lands at the barrier
      size_t off = (size_t)(kt + 1) * 4096;
#pragma unroll
      for (int j = 0; j < 2; j++) {
        gload16(kbase + off + j * 512, &Ks[cur ^ 1][w * 16 + j * 8][0]);
        gload16(vbase + off + j * 512, &Vs[cur ^ 1][w * 16 + j * 8][0]);
      }
    }

    // ---- QK^T swapped: st[kvh] = S^T tile (32 kv x 32 q) ----
    f32x16 st[2];
#pragma unroll
    for (int kvh = 0; kvh < 2; kvh++)
#pragma unroll
      for (int r = 0; r < 16; r++) st[kvh][r] = 0.f;
    __builtin_amdgcn_s_setprio(1);
#pragma unroll
    for (int kc = 0; kc < 4; kc++) {
      bf16x8 ka0 = *reinterpret_cast<const bf16x8*>(
          &Ks[cur][l31][((2 * kc + hi) ^ swz) * 8]);
      bf16x8 ka1 = *reinterpret_cast<const bf16x8*>(
          &Ks[cur][32 + l31][((2 * kc + hi) ^ swz) * 8]);
      st[0] = __builtin_amdgcn_mfma_f32_32x32x16_bf16(ka0, qb[kc], st[0], 0, 0, 0);
      st[1] = __builtin_amdgcn_mfma_f32_32x32x16_bf16(ka1, qb[kc], st[1], 0, 0, 0);
    }
    __builtin_amdgcn_s_setprio(0);

    // causal mask: lane's value (kvh,r) is kv = kt*64 + 32*kvh + crow(r,hi)
    if (kt >= 2 * qt) {
      int kvb = kt * 64;
#pragma unroll
      for (int kvh = 0; kvh < 2; kvh++)
#pragma unroll
        for (int r = 0; r < 16; r++) {
          int kv = kvb + kvh * 32 + (r & 3) + 8 * (r >> 2) + 4 * hi;
          if (kv > qrow) st[kvh][r] = NEG;
        }
    }

    // fixed-max softmax numerator (log2-domain), in place; rs is lane-local
#pragma unroll
    for (int kvh = 0; kvh < 2; kvh++)
#pragma unroll
      for (int r = 0; r < 16; r++) {
        float p = exp2f(st[kvh][r]);
        st[kvh][r] = p;
        rs += p;
      }

    // P -> bf16 PV A-fragments in-register: per ks, 4 cvt_pk + 2 permlane
    bf16x8 pa[4];
#pragma unroll
    for (int ks = 0; ks < 4; ks++) {
      const f32x16& pp = st[ks >> 1];
      const int s8 = (ks & 1) * 8;
      uint32_t x0 = cvtpk(pp[s8 + 0], pp[s8 + 1]);
      uint32_t x1 = cvtpk(pp[s8 + 2], pp[s8 + 3]);
      uint32_t y0 = cvtpk(pp[s8 + 4], pp[s8 + 5]);
      uint32_t y1 = cvtpk(pp[s8 + 6], pp[s8 + 7]);
      pl32swap(x0, y0);  // x0 -> word0 (j=0,1), y0 -> word2 (j=4,5)
      pl32swap(x1, y1);  // x1 -> word1 (j=2,3), y1 -> word3 (j=6,7)
      uint32_t wds[4] = {x0, x1, y0, y1};
      pa[ks] = *reinterpret_cast<const bf16x8*>(wds);
    }

    // ---- PV: accO[dh] (32q x 32d) += pa[ks] * V[ks-chunk][dh-half] ----
    __builtin_amdgcn_s_setprio(1);
#pragma unroll
    for (int dh = 0; dh < 2; dh++)
#pragma unroll
      for (int ks = 0; ks < 4; ks++) {
        bf16x8 vb = *reinterpret_cast<const bf16x8*>(
            &Vs[cur][dh * 32 + l31][((2 * ks + hi) ^ swz) * 8]);
        accO[dh] = __builtin_amdgcn_mfma_f32_32x32x16_bf16(pa[ks], vb, accO[dh], 0, 0, 0);
      }
    __builtin_amdgcn_s_setprio(0);
    __syncthreads();  // single barrier: LDS reads done + prefetch DMA landed
  }

  // ---- epilogue: full row-sum, broadcast 1/rs via tiny LDS, write O ----
  rs += __shfl_xor(rs, 32, 64);
  if (hi == 0) rsbuf[w][l31] = rs;
  __syncthreads();
#pragma unroll
  for (int r = 0; r < 16; r++) {
    int ql = (r & 3) + 8 * (r >> 2) + 4 * hi;   // local q-row of accO[.][r]
    float inv = 1.f / rsbuf[w][ql];
    int prow = qt * 128 + w * 32 + ql;
    size_t base = ((size_t)(b * 2048 + prow)) * 1024 + h * 64;
    A[base + l31] = f2bf(accO[0][r] * inv);
    A[base + 32 + l31] = f2bf(accO[1][r] * inv);
  }
}

extern "C" void kernel_launch(void* const* d_in, const int* in_sizes, int n_in,
                              void* d_out, int out_size, void* d_ws, size_t ws_size,
                              hipStream_t stream) {
  const float* X  = (const float*)d_in[0];  // residual_stream [2][2048][1024]
  const float* Wq = (const float*)d_in[1];  // weight_query [16][1024][64]
  const float* Wk = (const float*)d_in[2];  // weight_key   [16][1024][64]
  const float* Wv = (const float*)d_in[3];  // weight_value [16][1024][64]
  const float* Wo = (const float*)d_in[4];  // weight_out   [1024][1024]
  float* out = (float*)d_out;               // [2][2048][1024] f32

  // WqT,WkT,WvT contiguous -> one BT stack [3072][1024] for the fused QKV GEMM.
  u16* ws = (u16*)d_ws;
  u16* WqT = ws;                    // [16][64][1024]
  u16* WoT = WqT + 3145728;         // [1024][1024]
  u16* Xb  = WoT + 1048576;         // [4096][1024] bf16 (dead after qkv)
  u16* Qb  = Xb + 4194304;          // [32][2048][64]
  u16* Kb  = Qb + 4194304;          // [32][2048][64]
  u16* VT2 = Kb + 4194304;          // [32][32][64][64] tile-blocked
  u16* Ab  = Xb;                    // aliases Xb; total 40 MB

  xcvt_k<<<dim3(2048), 256, 0, stream>>>(X, Xb);
  transpose_qkv_k<<<dim3(16, 1, 48), 256, 0, stream>>>(Wq, Wk, Wv, WqT);
  transpose_cvt_k<<<dim3(16, 16, 1), 256, 0, stream>>>(Wo, WoT, 1024, 1024);

  qkv_gemm128_k<<<dim3(32, 24), 256, 0, stream>>>(Xb, WqT, Qb, Kb, VT2);
  attn_k<<<dim3(16, 16, 2), 256, 0, stream>>>(Qb, Kb, VT2, Ab);
  out_gemm128_k<<<dim3(32, 8), 256, 0, stream>>>(Ab, WoT, out);
}

// Round 6
// 203.166 us; speedup vs baseline: 1.1220x; 1.0692x over previous
//
#include <hip/hip_runtime.h>
#include <hip/hip_bf16.h>
#include <stdint.h>

// MultiHeadAttention: B=2, P=2048, D_MODEL=1024, H=16, D=64, causal.
//
// R17: gemm128_core converted to depth-2 counted-vmcnt pipeline (T4,
// m201/m218 pattern). R15/R16's "pipeline" used __syncthreads, whose
// implicit s_waitcnt vmcnt(0) drained the just-issued prefetch every
// step -> exposed ~2000+ cyc/step (qkv 60-66us, MfmaUtil 15%, all pipes
// idle). Now: prologue issues steps 0,1; per step s: vmcnt(8) [L(s)
// landed, L(s+1) in flight] -> s_barrier -> sched_barrier(0) -> MFMA on
// buf[s&1] -> sched_barrier(0) -> s_barrier -> issue L(s+2) into the
// buffer just read. vmcnt never drains to 0 in the main loop (T4);
// loads span a full step. attn_k unchanged from R16 for attribution.

typedef __bf16 bf16x8 __attribute__((ext_vector_type(8)));
typedef float f32x4 __attribute__((ext_vector_type(4)));
typedef float f32x16 __attribute__((ext_vector_type(16)));
typedef unsigned short u16;

__device__ __forceinline__ u16 f2bf(float f) {
  unsigned u = __float_as_uint(f);
  u += 0x7fffu + ((u >> 16) & 1u);
  return (u16)(u >> 16);
}

__device__ __forceinline__ uint32_t cvtpk(float lo, float hi) {
  uint32_t r;
  asm("v_cvt_pk_bf16_f32 %0, %1, %2" : "=v"(r) : "v"(lo), "v"(hi));
  return r;
}

// v_permlane32_swap_b32: a' = {a_low, b_low-to-high}, b' = {a_high-to-low, b_high}
__device__ __forceinline__ void pl32swap(uint32_t& a, uint32_t& b) {
  asm volatile("v_permlane32_swap_b32 %0, %1" : "+v"(a), "+v"(b));
}

// ---- X f32 -> bf16 (coalesced, 8 elems/thread) ----
__global__ __launch_bounds__(256) void xcvt_k(const float* __restrict__ in,
                                              u16* __restrict__ out) {
  int i = (blockIdx.x * 256 + threadIdx.x) * 8;
  float4 f0 = *reinterpret_cast<const float4*>(in + i);
  float4 f1 = *reinterpret_cast<const float4*>(in + i + 4);
  u16 tmp[8] = {f2bf(f0.x), f2bf(f0.y), f2bf(f0.z), f2bf(f0.w),
                f2bf(f1.x), f2bf(f1.y), f2bf(f1.z), f2bf(f1.w)};
  *reinterpret_cast<uint4*>(out + i) = *reinterpret_cast<uint4*>(tmp);
}

// ---- generic weight transpose+convert: in f32 [B][R][C] -> out bf16 [B][C][R] ----
__global__ __launch_bounds__(256) void transpose_cvt_k(const float* __restrict__ in,
                                                       u16* __restrict__ out,
                                                       int R, int C) {
  __shared__ u16 tile[64][80];
  int b = blockIdx.z;
  int r0 = blockIdx.x * 64, c0 = blockIdx.y * 64;
  const float* ip = in + (size_t)b * R * C;
  u16* op = out + (size_t)b * R * C;
  int t = threadIdx.x;
  int r = t >> 2, cb = (t & 3) * 16;
  const float4* src = reinterpret_cast<const float4*>(ip + (size_t)(r0 + r) * C + c0 + cb);
  u16 tmp[16];
#pragma unroll
  for (int v = 0; v < 4; v++) {
    float4 f = src[v];
    tmp[v * 4 + 0] = f2bf(f.x);
    tmp[v * 4 + 1] = f2bf(f.y);
    tmp[v * 4 + 2] = f2bf(f.z);
    tmp[v * 4 + 3] = f2bf(f.w);
  }
  *reinterpret_cast<uint4*>(&tile[r][cb]) = *reinterpret_cast<uint4*>(&tmp[0]);
  *reinterpret_cast<uint4*>(&tile[r][cb + 8]) = *reinterpret_cast<uint4*>(&tmp[8]);
  __syncthreads();
  int c = t >> 2, rb = (t & 3) * 16;
  uint4 outv[2];
  u16* tp = reinterpret_cast<u16*>(outv);
#pragma unroll
  for (int j = 0; j < 16; j++) tp[j] = tile[rb + j][c];
  uint4* dst = reinterpret_cast<uint4*>(op + (size_t)(c0 + c) * R + r0 + rb);
  dst[0] = outv[0];
  dst[1] = outv[1];
}

// ---- fused q/k/v weight transpose: z = 0..47 -> (sel = z>>4, head = z&15) ----
__global__ __launch_bounds__(256) void transpose_qkv_k(const float* __restrict__ Wq,
                                                       const float* __restrict__ Wk,
                                                       const float* __restrict__ Wv,
                                                       u16* __restrict__ outBase) {
  __shared__ u16 tile[64][80];
  int z = blockIdx.z;
  int sel = z >> 4, head = z & 15;
  const float* W = (sel == 0) ? Wq : (sel == 1 ? Wk : Wv);
  const float* ip = W + (size_t)head * 65536;           // [1024][64]
  u16* op = outBase + (size_t)sel * 1048576 + (size_t)head * 65536;  // [64][1024]
  int r0 = blockIdx.x * 64;                              // row block in R=1024
  int t = threadIdx.x;
  int r = t >> 2, cb = (t & 3) * 16;
  const float4* src = reinterpret_cast<const float4*>(ip + (size_t)(r0 + r) * 64 + cb);
  u16 tmp[16];
#pragma unroll
  for (int v = 0; v < 4; v++) {
    float4 f = src[v];
    tmp[v * 4 + 0] = f2bf(f.x);
    tmp[v * 4 + 1] = f2bf(f.y);
    tmp[v * 4 + 2] = f2bf(f.z);
    tmp[v * 4 + 3] = f2bf(f.w);
  }
  *reinterpret_cast<uint4*>(&tile[r][cb]) = *reinterpret_cast<uint4*>(&tmp[0]);
  *reinterpret_cast<uint4*>(&tile[r][cb + 8]) = *reinterpret_cast<uint4*>(&tmp[8]);
  __syncthreads();
  int c = t >> 2, rb = (t & 3) * 16;
  uint4 outv[2];
  u16* tp = reinterpret_cast<u16*>(outv);
#pragma unroll
  for (int j = 0; j < 16; j++) tp[j] = tile[rb + j][c];
  uint4* dst = reinterpret_cast<uint4*>(op + (size_t)c * 1024 + r0 + rb);
  dst[0] = outv[0];
  dst[1] = outv[1];
}

// ---- direct global->LDS DMA, 16B per lane (dest = wave-uniform base + lane*16) ----
__device__ __forceinline__ void gload16(const u16* g, u16* l) {
  __builtin_amdgcn_global_load_lds(
      (__attribute__((address_space(1))) void*)(g),
      (__attribute__((address_space(3))) void*)(l), 16, 0, 0);
}

// ====== 128x128 GEMM core: depth-2 counted-vmcnt pipeline (T4) ======
// LDS rows are 128B (linear dest, as gload_lds needs). Swizzle (rule #21):
// 16B chunk p at row r holds global chunk p ^ (r&7); stage pre-swizzles the
// per-lane SOURCE col, reads XOR their chunk index -> reads <=2-way.
// Each wave issues exactly 8 gloads per K-step; vmcnt(8) therefore means
// "my previous step's loads have landed". Barrier #1 (post-vmcnt) makes
// that true for ALL waves before anyone reads; barrier #2 protects the
// buffer from the overwrite DMA issued right after it.
__device__ __forceinline__ void gemm128_core(const u16* __restrict__ A,
                                             const u16* __restrict__ BT,
                                             int m0, int n0,
                                             f32x4 (&acc)[4][4]) {
  __shared__ __align__(16) u16 As[2][128][64];
  __shared__ __align__(16) u16 Bs[2][128][64];
  int t = threadIdx.x, l = t & 63;
  int w = t >> 6, wm = w & 1, wn = w >> 1;
  int l15 = l & 15, q4 = l >> 4;
  int r8 = l >> 3;                   // row within an 8-row gload group
  int cs = ((l & 7) ^ r8) * 8;       // pre-swizzled source chunk (u16 units)
  int swz = l15 & 7;                 // read-side row XOR key
  int srow = w * 32 + r8;
  const u16* ga = A + (size_t)(m0 + srow) * 1024 + cs;
  const u16* gb = BT + (size_t)(n0 + srow) * 1024 + cs;
  f32x4 z4 = {0.f, 0.f, 0.f, 0.f};
#pragma unroll
  for (int mi = 0; mi < 4; mi++)
#pragma unroll
    for (int nt = 0; nt < 4; nt++) acc[mi][nt] = z4;

  // prologue: issue K-steps 0 and 1 (16 loads/wave outstanding, no wait)
#pragma unroll
  for (int i = 0; i < 4; i++) {
    gload16(ga + (size_t)(i * 8) * 1024, &As[0][w * 32 + i * 8][0]);
    gload16(gb + (size_t)(i * 8) * 1024, &Bs[0][w * 32 + i * 8][0]);
  }
#pragma unroll
  for (int i = 0; i < 4; i++) {
    gload16(ga + (size_t)(i * 8) * 1024 + 64, &As[1][w * 32 + i * 8][0]);
    gload16(gb + (size_t)(i * 8) * 1024 + 64, &Bs[1][w * 32 + i * 8][0]);
  }

  for (int step = 0; step < 16; step++) {
    int cur = step & 1;
    // wait for THIS step's data; keep next step's 8 loads in flight (T4)
    if (step < 15)
      asm volatile("s_waitcnt vmcnt(8)" ::: "memory");
    else
      asm volatile("s_waitcnt vmcnt(0)" ::: "memory");
    __builtin_amdgcn_s_barrier();          // all waves' step-s data landed
    __builtin_amdgcn_sched_barrier(0);     // rule #18: pin reads below
#pragma unroll
    for (int kk = 0; kk < 2; kk++) {
      bf16x8 af[4], bfr[4];
#pragma unroll
      for (int mi = 0; mi < 4; mi++)
        af[mi] = *reinterpret_cast<const bf16x8*>(
            &As[cur][wm * 64 + mi * 16 + l15][((kk * 4 + q4) ^ swz) * 8]);
#pragma unroll
      for (int nt = 0; nt < 4; nt++)
        bfr[nt] = *reinterpret_cast<const bf16x8*>(
            &Bs[cur][wn * 64 + nt * 16 + l15][((kk * 4 + q4) ^ swz) * 8]);
#pragma unroll
      for (int mi = 0; mi < 4; mi++)
#pragma unroll
        for (int nt = 0; nt < 4; nt++)
          acc[mi][nt] = __builtin_amdgcn_mfma_f32_16x16x32_bf16(af[mi], bfr[nt], acc[mi][nt], 0, 0, 0);
    }
    __builtin_amdgcn_sched_barrier(0);     // reads stay above barrier #2
    __builtin_amdgcn_s_barrier();          // all waves done reading buf[cur]
    if (step + 2 < 16) {                   // refill the buffer just read
      int k0 = (step + 2) * 64;
#pragma unroll
      for (int i = 0; i < 4; i++) {
        gload16(ga + (size_t)(i * 8) * 1024 + k0, &As[cur][w * 32 + i * 8][0]);
        gload16(gb + (size_t)(i * 8) * 1024 + k0, &Bs[cur][w * 32 + i * 8][0]);
      }
    }
  }
}

// QKV: A=Xb [4096][1024], BT=[WqT|WkT|WvT] [3072][1024]; grid (32, 24).
// V written tile-blocked: VT2[bh][ktile(32)][d(64)][pc(64)].
__global__ __launch_bounds__(256) void qkv_gemm128_k(const u16* __restrict__ A,
                                                     const u16* __restrict__ BT,
                                                     u16* __restrict__ Q,
                                                     u16* __restrict__ K,
                                                     u16* __restrict__ VT2) {
  const float QSCALE = 0.125f * 1.44269504088896340736f;  // (1/sqrt(64))*log2(e)
  int m0 = blockIdx.x * 128, n0 = blockIdx.y * 128;
  f32x4 acc[4][4];
  gemm128_core(A, BT, m0, n0, acc);
  int t = threadIdx.x, l = t & 63;
  int w = t >> 6, wm = w & 1, wn = w >> 1;
  int l15 = l & 15, q4 = l >> 4;
#pragma unroll
  for (int mi = 0; mi < 4; mi++) {
#pragma unroll
    for (int nt = 0; nt < 4; nt++) {
#pragma unroll
      for (int r = 0; r < 4; r++) {
        int m = m0 + wm * 64 + mi * 16 + q4 * 4 + r;
        int n = n0 + wn * 64 + nt * 16 + l15;
        int wsel = n >> 10, h = (n >> 6) & 15, d = n & 63;
        int b = m >> 11, p = m & 2047;
        size_t bh = (size_t)(b * 16 + h);
        float v = acc[mi][nt][r];
        if (wsel == 0)
          Q[(bh * 2048 + p) * 64 + d] = f2bf(v * QSCALE);
        else if (wsel == 1)
          K[(bh * 2048 + p) * 64 + d] = f2bf(v);
        else
          VT2[((bh * 32 + (p >> 6)) * 64 + d) * 64 + (p & 63)] = f2bf(v);
      }
    }
  }
}

// OUT: A=Ab [4096][1024], BT=WoT [1024][1024], O f32; grid (32, 8).
__global__ __launch_bounds__(256) void out_gemm128_k(const u16* __restrict__ A,
                                                     const u16* __restrict__ BT,
                                                     float* __restrict__ O) {
  int m0 = blockIdx.x * 128, n0 = blockIdx.y * 128;
  f32x4 acc[4][4];
  gemm128_core(A, BT, m0, n0, acc);
  int t = threadIdx.x, l = t & 63;
  int w = t >> 6, wm = w & 1, wn = w >> 1;
  int l15 = l & 15, q4 = l >> 4;
#pragma unroll
  for (int mi = 0; mi < 4; mi++) {
#pragma unroll
    for (int nt = 0; nt < 4; nt++) {
#pragma unroll
      for (int r = 0; r < 4; r++) {
        int m = m0 + wm * 64 + mi * 16 + q4 * 4 + r;
        int n = n0 + wn * 64 + nt * 16 + l15;
        O[(size_t)m * 1024 + n] = acc[mi][nt][r];
      }
    }
  }
}

// ---- flash attention: 32x32 swapped-QK^T, in-register softmax (T12) ----
// grid (16,16,2) = 512 blocks -> 2/CU; qt = b?15-pr:pr balances CU pairs.
// Wave w owns 32 q-rows (col=l&31 of the S^T tile). Per kt-iter:
// prefetch next K/V tile (gload_lds, XOR-swizzled source) -> S^T = mfma(K,Q)
// -> mask/exp2 in-register -> cvt_pk+permlane32_swap builds PV A-frags
// -> accO += mfma(pa, V) -> one barrier. P never touches LDS.
__global__ __launch_bounds__(256) void attn_k(const u16* __restrict__ Q,
                                              const u16* __restrict__ K,
                                              const u16* __restrict__ VT2,
                                              u16* __restrict__ A) {
  __shared__ __align__(16) u16 Ks[2][64][64];
  __shared__ __align__(16) u16 Vs[2][64][64];
  __shared__ float rsbuf[4][32];
  int pr = blockIdx.x, h = blockIdx.y, b = blockIdx.z;
  int qt = b ? (15 - pr) : pr;
  size_t bh = (size_t)(b * 16 + h);
  const u16* Qp = Q + bh * 2048 * 64;
  const u16* Kp = K + bh * 2048 * 64;
  const u16* Vt = VT2 + bh * 32 * 64 * 64;   // [kt][d(64)][pc(64)]
  int t = threadIdx.x, l = t & 63, w = t >> 6;
  int l31 = l & 31, hi = l >> 5;
  int r8 = l >> 3, cs = ((l & 7) ^ r8) * 8;  // staging source pre-swizzle
  int swz = l31 & 7;                          // fragment-read XOR key (row&7)
  const float NEG = -1e30f;
  int nkt = 2 * qt + 2;
  // wave w stages rows [w*16, w*16+16) of both tiles; 2 gloads each of K and V
  const u16* kbase = Kp + (size_t)(w * 16 + r8) * 64 + cs;
  const u16* vbase = Vt + (size_t)(w * 16 + r8) * 64 + cs;
  int qrow = qt * 128 + w * 32 + l31;        // this lane's q-row (S^T col)

  // Q as B-operand: qb[kc][j] = Q[qrow][d = 16*kc + 8*hi + j]
  bf16x8 qb[4];
#pragma unroll
  for (int kc = 0; kc < 4; kc++)
    qb[kc] = *reinterpret_cast<const bf16x8*>(Qp + (size_t)qrow * 64 + kc * 16 + hi * 8);

  f32x16 accO[2];
#pragma unroll
  for (int dh = 0; dh < 2; dh++)
#pragma unroll
    for (int r = 0; r < 16; r++) accO[dh][r] = 0.f;
  float rs = 0.f;

  // prologue: DMA tile kt=0 into buffer 0
#pragma unroll
  for (int j = 0; j < 2; j++) {
    gload16(kbase + (size_t)(j * 512), &Ks[0][w * 16 + j * 8][0]);
    gload16(vbase + (size_t)(j * 512), &Vs[0][w * 16 + j * 8][0]);
  }
  __syncthreads();

  for (int kt = 0; kt < nkt; kt++) {
    int cur = kt & 1;
    if (kt < nkt - 1) {  // prefetch next tile into buf^1; lands at the barrier
      size_t off = (size_t)(kt + 1) * 4096;
#pragma unroll
      for (int j = 0; j < 2; j++) {
        gload16(kbase + off + j * 512, &Ks[cur ^ 1][w * 16 + j * 8][0]);
        gload16(vbase + off + j * 512, &Vs[cur ^ 1][w * 16 + j * 8][0]);
      }
    }

    // ---- QK^T swapped: st[kvh] = S^T tile (32 kv x 32 q) ----
    f32x16 st[2];
#pragma unroll
    for (int kvh = 0; kvh < 2; kvh++)
#pragma unroll
      for (int r = 0; r < 16; r++) st[kvh][r] = 0.f;
    __builtin_amdgcn_s_setprio(1);
#pragma unroll
    for (int kc = 0; kc < 4; kc++) {
      bf16x8 ka0 = *reinterpret_cast<const bf16x8*>(
          &Ks[cur][l31][((2 * kc + hi) ^ swz) * 8]);
      bf16x8 ka1 = *reinterpret_cast<const bf16x8*>(
          &Ks[cur][32 + l31][((2 * kc + hi) ^ swz) * 8]);
      st[0] = __builtin_amdgcn_mfma_f32_32x32x16_bf16(ka0, qb[kc], st[0], 0, 0, 0);
      st[1] = __builtin_amdgcn_mfma_f32_32x32x16_bf16(ka1, qb[kc], st[1], 0, 0, 0);
    }
    __builtin_amdgcn_s_setprio(0);

    // causal mask: lane's value (kvh,r) is kv = kt*64 + 32*kvh + crow(r,hi)
    if (kt >= 2 * qt) {
      int kvb = kt * 64;
#pragma unroll
      for (int kvh = 0; kvh < 2; kvh++)
#pragma unroll
        for (int r = 0; r < 16; r++) {
          int kv = kvb + kvh * 32 + (r & 3) + 8 * (r >> 2) + 4 * hi;
          if (kv > qrow) st[kvh][r] = NEG;
        }
    }

    // fixed-max softmax numerator (log2-domain), in place; rs is lane-local
#pragma unroll
    for (int kvh = 0; kvh < 2; kvh++)
#pragma unroll
      for (int r = 0; r < 16; r++) {
        float p = exp2f(st[kvh][r]);
        st[kvh][r] = p;
        rs += p;
      }

    // P -> bf16 PV A-fragments in-register: per ks, 4 cvt_pk + 2 permlane
    bf16x8 pa[4];
#pragma unroll
    for (int ks = 0; ks < 4; ks++) {
      const f32x16& pp = st[ks >> 1];
      const int s8 = (ks & 1) * 8;
      uint32_t x0 = cvtpk(pp[s8 + 0], pp[s8 + 1]);
      uint32_t x1 = cvtpk(pp[s8 + 2], pp[s8 + 3]);
      uint32_t y0 = cvtpk(pp[s8 + 4], pp[s8 + 5]);
      uint32_t y1 = cvtpk(pp[s8 + 6], pp[s8 + 7]);
      pl32swap(x0, y0);  // x0 -> word0 (j=0,1), y0 -> word2 (j=4,5)
      pl32swap(x1, y1);  // x1 -> word1 (j=2,3), y1 -> word3 (j=6,7)
      uint32_t wds[4] = {x0, x1, y0, y1};
      pa[ks] = *reinterpret_cast<const bf16x8*>(wds);
    }

    // ---- PV: accO[dh] (32q x 32d) += pa[ks] * V[ks-chunk][dh-half] ----
    __builtin_amdgcn_s_setprio(1);
#pragma unroll
    for (int dh = 0; dh < 2; dh++)
#pragma unroll
      for (int ks = 0; ks < 4; ks++) {
        bf16x8 vb = *reinterpret_cast<const bf16x8*>(
            &Vs[cur][dh * 32 + l31][((2 * ks + hi) ^ swz) * 8]);
        accO[dh] = __builtin_amdgcn_mfma_f32_32x32x16_bf16(pa[ks], vb, accO[dh], 0, 0, 0);
      }
    __builtin_amdgcn_s_setprio(0);
    __syncthreads();  // single barrier: LDS reads done + prefetch DMA landed
  }

  // ---- epilogue: full row-sum, broadcast 1/rs via tiny LDS, write O ----
  rs += __shfl_xor(rs, 32, 64);
  if (hi == 0) rsbuf[w][l31] = rs;
  __syncthreads();
#pragma unroll
  for (int r = 0; r < 16; r++) {
    int ql = (r & 3) + 8 * (r >> 2) + 4 * hi;   // local q-row of accO[.][r]
    float inv = 1.f / rsbuf[w][ql];
    int prow = qt * 128 + w * 32 + ql;
    size_t base = ((size_t)(b * 2048 + prow)) * 1024 + h * 64;
    A[base + l31] = f2bf(accO[0][r] * inv);
    A[base + 32 + l31] = f2bf(accO[1][r] * inv);
  }
}

extern "C" void kernel_launch(void* const* d_in, const int* in_sizes, int n_in,
                              void* d_out, int out_size, void* d_ws, size_t ws_size,
                              hipStream_t stream) {
  const float* X  = (const float*)d_in[0];  // residual_stream [2][2048][1024]
  const float* Wq = (const float*)d_in[1];  // weight_query [16][1024][64]
  const float* Wk = (const float*)d_in[2];  // weight_key   [16][1024][64]
  const float* Wv = (const float*)d_in[3];  // weight_value [16][1024][64]
  const float* Wo = (const float*)d_in[4];  // weight_out   [1024][1024]
  float* out = (float*)d_out;               // [2][2048][1024] f32

  // WqT,WkT,WvT contiguous -> one BT stack [3072][1024] for the fused QKV GEMM.
  u16* ws = (u16*)d_ws;
  u16* WqT = ws;                    // [16][64][1024]
  u16* WoT = WqT + 3145728;         // [1024][1024]
  u16* Xb  = WoT + 1048576;         // [4096][1024] bf16 (dead after qkv)
  u16* Qb  = Xb + 4194304;          // [32][2048][64]
  u16* Kb  = Qb + 4194304;          // [32][2048][64]
  u16* VT2 = Kb + 4194304;          // [32][32][64][64] tile-blocked
  u16* Ab  = Xb;                    // aliases Xb; total 40 MB

  xcvt_k<<<dim3(2048), 256, 0, stream>>>(X, Xb);
  transpose_qkv_k<<<dim3(16, 1, 48), 256, 0, stream>>>(Wq, Wk, Wv, WqT);
  transpose_cvt_k<<<dim3(16, 16, 1), 256, 0, stream>>>(Wo, WoT, 1024, 1024);

  qkv_gemm128_k<<<dim3(32, 24), 256, 0, stream>>>(Xb, WqT, Qb, Kb, VT2);
  attn_k<<<dim3(16, 16, 2), 256, 0, stream>>>(Qb, Kb, VT2, Ab);
  out_gemm128_k<<<dim3(32, 8), 256, 0, stream>>>(Ab, WoT, out);
}